// Round 6
// baseline (163.030 us; speedup 1.0000x reference)
//
#include <hip/hip_runtime.h>

namespace {

typedef unsigned int uint;
typedef unsigned short ushort_t;
typedef __attribute__((ext_vector_type(8))) short bf16x8;
typedef __attribute__((ext_vector_type(4))) float f32x4;

constexpr int N = 4, T = 2048, L = 2048;
constexpr int DQIN = 32, DQK = 64;

// workspace layout (float-sized slots); ~6.5 MB
constexpr int VI_SZ = 3 * N * 64 * L;  // ushort pairs [dim row][8l-group][hi8|lo8], as float slots
constexpr int X_SZ = 3 * N * L;
constexpr int A_SZ = 3 * N * T;

union PK8 { int i[4]; bf16x8 s; };

// =================== fused prep kernel ===================
// [0,1536): V transform (4 rows/thread, float2 row loads);
// [1536,1568): Q->a,g for ALL 3 modalities (qr computed ONCE; Wq/Wk/bk read
//   via wave-uniform indices -> scalar s_loads from K$, zero LDS — the old
//   version did 512 ds_read_b128 per THREAD and computed qr 3x);
// [1568,1664): binary searches.
// V first: bulk work dispatches early; Q/search latency-tails overlap it.
__global__ __launch_bounds__(256) void mm_prep(
    const float* __restrict__ ref_data, const float* __restrict__ ref_t,
    const float* __restrict__ d1, const float* __restrict__ t1,
    const float* __restrict__ d2, const float* __restrict__ t2,
    const float* __restrict__ d3, const float* __restrict__ t3,
    const float* __restrict__ Wq,
    const float* __restrict__ Wk1, const float* __restrict__ bk1,
    const float* __restrict__ Wv1, const float* __restrict__ bv1, const float* __restrict__ lt1,
    const float* __restrict__ Wk2, const float* __restrict__ bk2,
    const float* __restrict__ Wv2, const float* __restrict__ bv2, const float* __restrict__ lt2,
    const float* __restrict__ Wk3, const float* __restrict__ bk3,
    const float* __restrict__ Wv3, const float* __restrict__ bv3, const float* __restrict__ lt3,
    float* __restrict__ Aq, float* __restrict__ Gq, int* __restrict__ Cq,
    ushort_t* __restrict__ VI, float* __restrict__ X) {
  const int b = blockIdx.x;
  const int tid = threadIdx.x;

  if (b < 1536) {
    // ---- V transform: 4 rows/thread ----
    const int vb = b;                 // 0..1535
    const int mn = vb >> 7;           // m*N+n
    const int m = mn >> 2, n = mn & 3;
    const int lseg = (vb & 127) * 16;
    const float* dm = (m == 0) ? d1 : (m == 1 ? d2 : d3);
    const float* Wv = (m == 0) ? Wv1 : (m == 1 ? Wv2 : Wv3);
    const float* bv = (m == 0) ? bv1 : (m == 1 ? bv2 : bv3);
    const int cdim = tid & 63;
    const int qq = tid >> 6;          // 0..3
    const int l0 = lseg + qq * 4;     // 4 rows per thread

    float Wc[32];
#pragma unroll
    for (int i = 0; i < 32; i++) Wc[i] = Wv[i * 64 + cdim];
    const float bvc = bv[cdim];

    uint hi16[4], lo16[4];
#pragma unroll
    for (int k = 0; k < 4; k++) {
      const float* dp = dm + (size_t)(n * L + l0 + k) * 34;
      float acc = bvc;
#pragma unroll
      for (int i = 0; i < 32; i += 2) {  // rows are 8B-aligned: float2 ok
        const float2 d2 = *(const float2*)&dp[i];
        acc = fmaf(d2.x, Wc[i], acc);
        acc = fmaf(d2.y, Wc[i + 1], acc);
      }
      uint u = __float_as_uint(acc);
      uint h = (u + 0x7fffu + ((u >> 16) & 1u)) & 0xffff0000u;
      float res = acc - __uint_as_float(h);
      uint ul = __float_as_uint(res);
      uint hl = (ul + 0x7fffu + ((ul >> 16) & 1u)) >> 16;
      hi16[k] = h >> 16;
      lo16[k] = hl;
    }
    const int pkh0 = (int)(hi16[0] | (hi16[1] << 16));
    const int pkh1 = (int)(hi16[2] | (hi16[3] << 16));
    const int pkl0 = (int)(lo16[0] | (lo16[1] << 16));
    const int pkl1 = (int)(lo16[2] | (lo16[3] << 16));
    // 4 rows = half an 8l-group at halfsel = (l0>>2)&1.
    ushort_t* dst = VI + (size_t)(mn * 64 + cdim) * (2 * L) +
                    (l0 >> 3) * 16 + ((l0 >> 2) & 1) * 4;
    *(int2*)dst = make_int2(pkh0, pkh1);
    *(int2*)(dst + 8) = make_int2(pkl0, pkl1);

    if (tid < 16) {
      const int l = lseg + tid;
      X[mn * L + l] = dm[(size_t)(n * L + l) * 34 + 33];
    }
  } else if (b < 1568) {
    // ---- Q path: one thread per t-row; qr once, 3 modality epilogues ----
    const int idx = (b - 1536) * 256 + tid;  // n*T + t
    float x[DQIN];
    const float* rp = ref_data + idx * DQIN;
#pragma unroll
    for (int i = 0; i < DQIN; i++) x[i] = rp[i];
    float qr[DQK];
#pragma unroll
    for (int j = 0; j < DQK; j += 4) {
      float4 acc4 = make_float4(0.f, 0.f, 0.f, 0.f);
#pragma unroll
      for (int i = 0; i < DQIN; i++) {
        // uniform index -> s_load_dwordx4 from K$ (no LDS, no sync)
        const float4 w = *(const float4*)&Wq[i * DQK + j];
        acc4.x = fmaf(x[i], w.x, acc4.x);
        acc4.y = fmaf(x[i], w.y, acc4.y);
        acc4.z = fmaf(x[i], w.z, acc4.z);
        acc4.w = fmaf(x[i], w.w, acc4.w);
      }
      qr[j] = acc4.x; qr[j + 1] = acc4.y; qr[j + 2] = acc4.z; qr[j + 3] = acc4.w;
    }
    const float* Wks[3] = {Wk1, Wk2, Wk3};
    const float* bks[3] = {bk1, bk2, bk3};
    const float* lts[3] = {lt1, lt2, lt3};
#pragma unroll
    for (int m = 0; m < 3; m++) {
      const float* Wk = Wks[m];
      const float* bk = bks[m];
      const float rs = __expf(-0.5f * lts[m][0]);
      float g = 0.f, h = 0.f;
#pragma unroll
      for (int j = 1; j < DQK; j++) {
        g = fmaf(qr[j], Wk[j - 1], g);   // uniform -> s_load
        h = fmaf(qr[j], bk[j - 1], h);
      }
      g += Wk[DQK - 1];
      h += bk[DQK - 1];
      Aq[m * (N * T) + idx] = (qr[0] - h) * rs;
      Gq[m * (N * T) + idx] = g * rs;
    }
  } else {
    // ---- binary searches ----
    const int sidx = (b - 1568) * 256 + tid;
    const int m = sidx >> 13;
    const int nt = sidx & 8191;
    const int n = nt >> 11;
    const float rt = ref_t[nt];
    const float* tml = ((m == 0) ? t1 : (m == 1 ? t2 : t3)) + n * L;
    int lo = 0, hi = L;
    while (lo < hi) {
      const int mid = (lo + hi) >> 1;
      if (tml[mid] <= rt) lo = mid + 1; else hi = mid;
    }
    Cq[m * 8192 + nt] = lo;
  }
}

// =================== main attention kernel (r4 winner, verbatim) ===================
// block = 2 waves, ONE rowgroup (16 t-rows) x full 64 dims; grid 12*128=1536
// (heavy-first -> 4 blocks/CU resident + 512-block LPT refill queue). The two
// waves split each 64-l chunk 32/32; exp+pack computed exactly once
// grid-wide. Counted vmcnt(8) ring, 2 raw barriers/chunk; cross-wave combine
// via LDS at the end. LDS 40KB.
__device__ inline void stage_chunk(ushort_t* dstbuf, const ushort_t* VIb, int ch,
                                   int w, int lane) {
#pragma unroll
  for (int i = 0; i < 8; i++) {
    const int n = (w * 8 + i) * 64 + lane;   // lds 16B-unit index 0..1023
    const int d = n >> 4;                    // dim row 0..63
    const int s = n & 15;                    // swizzled unit slot
    const int u = (s - d) & 15;              // original unit within row-chunk
    const ushort_t* src = VIb + (size_t)d * 4096 + ch * 128 + u * 8;
    __builtin_amdgcn_global_load_lds(
        (const __attribute__((address_space(1))) void*)src,
        (__attribute__((address_space(3))) void*)(dstbuf + n * 8),
        16, 0, 0);
  }
}

__global__ __launch_bounds__(128, 2) void mm_attn_main(
    const ushort_t* __restrict__ VI, const float* __restrict__ X,
    const float* __restrict__ Aq, const float* __restrict__ Gq, const int* __restrict__ Cq,
    float* __restrict__ out) {
  __shared__ ushort_t sbuf[2][8192];  // 2 x 16KB chunk slabs (64 dims x 64 l)
  __shared__ float sx[2048];          // full X row for this mn (8KB) -> 40KB

  const int b = blockIdx.x;
  const int mn = b % 12;
  const int rg = 127 - (b / 12);  // heavy rowgroups (large c) first

  const int tid = threadIdx.x;
  const int lane = tid & 63;
  const int w = tid >> 6;              // wave 0/1: l-half of each chunk
  const int q = lane >> 4;
  const int m16 = lane & 15;

  const int tbase = mn * T + rg * 16;

  const int c = Cq[tbase + m16];
  const int cmax = __shfl(c, 15, 64);  // c monotone in t
  const int cmin = __shfl(c, 0, 64);
  const int nch = (cmax + 63) >> 6;    // block-uniform chunk count

  const float a = Aq[tbase + m16];
  const float g = Gq[tbase + m16];

  f32x4 acc[4];  // [hh*2+ct]: cols hh*32 + ct*16 + m16 (partial over this wave's l)
#pragma unroll
  for (int i = 0; i < 4; i++) acc[i] = (f32x4){0.f, 0.f, 0.f, 0.f};
  float z = 0.f;

  const ushort_t* VIb = VI + (size_t)(mn * 64) * 4096;
  const float* xg = X + mn * L;

  // hoisted swizzled B-fragment offsets (ushorts): dim row d, unit u stored
  // at d*16 + ((u+d)&15); this wave reads groups w*4+q (hi/lo parts).
  int oh[2][2], ol[2][2];
#pragma unroll
  for (int hh = 0; hh < 2; hh++) {
#pragma unroll
    for (int ct = 0; ct < 2; ct++) {
      const int d = hh * 32 + ct * 16 + m16;
      const int u0 = (w * 4 + q) * 2;
      oh[hh][ct] = d * 128 + (((u0 + 0) + d) & 15) * 8;
      ol[hh][ct] = d * 128 + (((u0 + 1) + d) & 15) * 8;
    }
  }

  // prologue: stage X (8KB) + chunk 0
#pragma unroll
  for (int i = 0; i < 4; i++) {
    const float* src = xg + (i * 128 + tid) * 4;
    __builtin_amdgcn_global_load_lds(
        (const __attribute__((address_space(1))) void*)src,
        (__attribute__((address_space(3))) void*)(sx + (i * 128 + tid) * 4),
        16, 0, 0);
  }
  if (nch > 0) stage_chunk(sbuf[0], VIb, 0, w, lane);

  for (int ch = 0; ch < nch; ch++) {
    if (ch + 1 < nch) {
      stage_chunk(sbuf[(ch + 1) & 1], VIb, ch + 1, w, lane);
      asm volatile("s_waitcnt vmcnt(8)" ::: "memory");  // this chunk done; next in flight
    } else {
      asm volatile("s_waitcnt vmcnt(0)" ::: "memory");
    }
    asm volatile("" ::: "memory");
    __builtin_amdgcn_s_barrier();  // both waves' halves staged
    asm volatile("" ::: "memory");

    const int kbase = (ch << 6) + w * 32;  // this wave's 32-l k-tile
    if (kbase < cmax) {
      const int k0 = kbase + q * 8;
      const float4 xa = *(const float4*)&sx[k0];
      const float4 xb = *(const float4*)&sx[k0 + 4];
      const float xs[8] = {xa.x, xa.y, xa.z, xa.w, xb.x, xb.y, xb.z, xb.w};
      float wv[8];
      if (kbase + 32 <= cmin) {  // all 16 rows fully active in this k-tile
#pragma unroll
        for (int jj = 0; jj < 8; jj++) {
          const float d = fmaf(-g, xs[jj], a);
          wv[jj] = __expf(-d * d);
          z += wv[jj];
        }
      } else {
#pragma unroll
        for (int jj = 0; jj < 8; jj++) {
          const float d = fmaf(-g, xs[jj], a);
          const float e = __expf(-d * d);
          wv[jj] = (k0 + jj < c) ? e : 0.f;
          z += wv[jj];
        }
      }
      PK8 ph, pl;
#pragma unroll
      for (int p2 = 0; p2 < 4; p2++) {
        const uint u0 = __float_as_uint(wv[2 * p2]);
        const uint u1 = __float_as_uint(wv[2 * p2 + 1]);
        const uint h0 = u0 & 0xffff0000u, h1 = u1 & 0xffff0000u;
        const float l0f = wv[2 * p2] - __uint_as_float(h0);
        const float l1f = wv[2 * p2 + 1] - __uint_as_float(h1);
        ph.i[p2] = (int)((h0 >> 16) | h1);
        pl.i[p2] = (int)((__float_as_uint(l0f) >> 16) | (__float_as_uint(l1f) & 0xffff0000u));
      }
      const bf16x8 ahi = ph.s, alo = pl.s;
      const ushort_t* buf = sbuf[ch & 1];
#pragma unroll
      for (int hh = 0; hh < 2; hh++) {
#pragma unroll
        for (int ct = 0; ct < 2; ct++) {
          const bf16x8 bh = *(const bf16x8*)(buf + oh[hh][ct]);
          const bf16x8 bl = *(const bf16x8*)(buf + ol[hh][ct]);
          acc[hh * 2 + ct] =
              __builtin_amdgcn_mfma_f32_16x16x32_bf16(ahi, bh, acc[hh * 2 + ct], 0, 0, 0);
          acc[hh * 2 + ct] =
              __builtin_amdgcn_mfma_f32_16x16x32_bf16(ahi, bl, acc[hh * 2 + ct], 0, 0, 0);
          acc[hh * 2 + ct] =
              __builtin_amdgcn_mfma_f32_16x16x32_bf16(alo, bh, acc[hh * 2 + ct], 0, 0, 0);
        }
      }
    }

    asm volatile("" ::: "memory");
    __builtin_amdgcn_s_barrier();  // reads done before next stage overwrites
    asm volatile("" ::: "memory");
  }

  // z: reduce q-replicas (each octet covered disjoint l within this wave)
  z += __shfl_xor(z, 16, 64);
  z += __shfl_xor(z, 32, 64);

  // cross-wave combine via LDS: wave w outputs dims [w*32, w*32+32) and
  // hands its partial of the OTHER half (quadrants hh = w^1) across.
  float* sc = (float*)sbuf;
  const int ow = w ^ 1;
#pragma unroll
  for (int p = 0; p < 2; p++)
    *(f32x4*)&sc[((w * 2 + p) * 64 + lane) * 4] = acc[ow * 2 + p];
  sc[1024 + w * 64 + lane] = z;
  __syncthreads();
  const float zt = z + sc[1024 + ow * 64 + lane];
  f32x4 r[2];
#pragma unroll
  for (int p = 0; p < 2; p++)
    r[p] = acc[w * 2 + p] + *(const f32x4*)&sc[((ow * 2 + p) * 64 + lane) * 4];

#pragma unroll
  for (int rr = 0; rr < 4; rr++) {
    const int row = q * 4 + rr;
    const float zr = __shfl(zt, row, 64);
    const int cr = __shfl(c, row, 64);
    const float inv = 1.0f / (zr + (float)(L - cr));
#pragma unroll
    for (int p = 0; p < 2; p++) {
      out[(size_t)(tbase + row) * 64 + w * 32 + p * 16 + m16] = r[p][rr] * inv;
    }
  }
}

}  // namespace

extern "C" void kernel_launch(void* const* d_in, const int* in_sizes, int n_in,
                              void* d_out, int out_size, void* d_ws, size_t ws_size,
                              hipStream_t stream) {
  const float* ref_data = (const float*)d_in[0];
  const float* ref_t = (const float*)d_in[1];
  const float* m1_data = (const float*)d_in[2];
  const float* m1_t = (const float*)d_in[3];
  const float* m2_data = (const float*)d_in[4];
  const float* m2_t = (const float*)d_in[5];
  const float* m3_data = (const float*)d_in[6];
  const float* m3_t = (const float*)d_in[7];
  const float* Wq = (const float*)d_in[8];
  const float* Wk1 = (const float*)d_in[9];
  const float* bk1 = (const float*)d_in[10];
  const float* Wv1 = (const float*)d_in[11];
  const float* bv1 = (const float*)d_in[12];
  const float* lt1 = (const float*)d_in[13];
  const float* Wk2 = (const float*)d_in[14];
  const float* bk2 = (const float*)d_in[15];
  const float* Wv2 = (const float*)d_in[16];
  const float* bv2 = (const float*)d_in[17];
  const float* lt2 = (const float*)d_in[18];
  const float* Wk3 = (const float*)d_in[19];
  const float* bk3 = (const float*)d_in[20];
  const float* Wv3 = (const float*)d_in[21];
  const float* bv3 = (const float*)d_in[22];
  const float* lt3 = (const float*)d_in[23];

  float* ws = (float*)d_ws;
  ushort_t* VI = (ushort_t*)ws;                 // VI_SZ float slots
  float* Xw = ws + VI_SZ;                       // X_SZ
  float* Aq = Xw + X_SZ;                        // A_SZ
  float* Gq = Aq + A_SZ;                        // A_SZ
  int* Cq = (int*)(Gq + A_SZ);                  // A_SZ

  mm_prep<<<dim3(1664), dim3(256), 0, stream>>>(
      ref_data, ref_t, m1_data, m1_t, m2_data, m2_t, m3_data, m3_t, Wq,
      Wk1, bk1, Wv1, bv1, lt1, Wk2, bk2, Wv2, bv2, lt2, Wk3, bk3, Wv3, bv3, lt3,
      Aq, Gq, Cq, VI, Xw);
  mm_attn_main<<<dim3(12 * 128), dim3(128), 0, stream>>>(
      VI, Xw, Aq, Gq, Cq, (float*)d_out);
}

// Round 7
// 147.576 us; speedup vs baseline: 1.1047x; 1.1047x over previous
//
#include <hip/hip_runtime.h>

namespace {

typedef unsigned int uint;
typedef unsigned short ushort_t;
typedef __attribute__((ext_vector_type(8))) short bf16x8;
typedef __attribute__((ext_vector_type(4))) float f32x4;

constexpr int N = 4, T = 2048, L = 2048;
constexpr int DQIN = 32, DQK = 64;

// workspace layout (float-sized slots); ~6.5 MB
constexpr int VI_SZ = 3 * N * 64 * L;  // ushort pairs [dim row][8l-group][hi8|lo8], as float slots
constexpr int X_SZ = 3 * N * L;
constexpr int A_SZ = 3 * N * T;

union PK8 { int i[4]; bf16x8 s; };

// =================== fused prep kernel ===================
// [0,32): Q->a,g for ALL 3 modalities (qr computed ONCE per t-row; Wq/Wk/bk
//   staged in LDS — broadcast ds_reads). Dispatched FIRST so these
//   latency-chained blocks hide under the V bulk (r6 put them at the tail:
//   prep ended 45.6us with 10% occupancy — an empty-machine tail).
// [32,128): binary searches (latency chains, also hidden under V).
// [128,1664): V transform (4 rows/thread, float2 row loads) — the bulk;
//   drains evenly, forms the kernel's tail.
__global__ __launch_bounds__(256) void mm_prep(
    const float* __restrict__ ref_data, const float* __restrict__ ref_t,
    const float* __restrict__ d1, const float* __restrict__ t1,
    const float* __restrict__ d2, const float* __restrict__ t2,
    const float* __restrict__ d3, const float* __restrict__ t3,
    const float* __restrict__ Wq,
    const float* __restrict__ Wk1, const float* __restrict__ bk1,
    const float* __restrict__ Wv1, const float* __restrict__ bv1, const float* __restrict__ lt1,
    const float* __restrict__ Wk2, const float* __restrict__ bk2,
    const float* __restrict__ Wv2, const float* __restrict__ bv2, const float* __restrict__ lt2,
    const float* __restrict__ Wk3, const float* __restrict__ bk3,
    const float* __restrict__ Wv3, const float* __restrict__ bv3, const float* __restrict__ lt3,
    float* __restrict__ Aq, float* __restrict__ Gq, int* __restrict__ Cq,
    ushort_t* __restrict__ VI, float* __restrict__ X) {
  const int b = blockIdx.x;
  const int tid = threadIdx.x;

  if (b < 32) {
    // ---- Q path: one thread per t-row; qr once, 3 modality epilogues ----
    const int idx = b * 256 + tid;  // n*T + t
    __shared__ float sWq[DQIN * DQK];
    __shared__ float sWk[3][DQK];
    __shared__ float sbk[3][DQK];
    for (int i = tid; i < DQIN * DQK; i += 256) sWq[i] = Wq[i];
    if (tid < DQK) {
      sWk[0][tid] = Wk1[tid]; sbk[0][tid] = bk1[tid];
      sWk[1][tid] = Wk2[tid]; sbk[1][tid] = bk2[tid];
      sWk[2][tid] = Wk3[tid]; sbk[2][tid] = bk3[tid];
    }
    __syncthreads();
    float x[DQIN];
    const float* rp = ref_data + idx * DQIN;
#pragma unroll
    for (int i = 0; i < DQIN; i++) x[i] = rp[i];
    float qr[DQK];
#pragma unroll
    for (int j = 0; j < DQK; j += 4) {
      float4 acc4 = make_float4(0.f, 0.f, 0.f, 0.f);
#pragma unroll
      for (int i = 0; i < DQIN; i++) {
        const float4 w = *(const float4*)&sWq[i * DQK + j];
        acc4.x = fmaf(x[i], w.x, acc4.x);
        acc4.y = fmaf(x[i], w.y, acc4.y);
        acc4.z = fmaf(x[i], w.z, acc4.z);
        acc4.w = fmaf(x[i], w.w, acc4.w);
      }
      qr[j] = acc4.x; qr[j + 1] = acc4.y; qr[j + 2] = acc4.z; qr[j + 3] = acc4.w;
    }
    const float* lts[3] = {lt1, lt2, lt3};
#pragma unroll
    for (int m = 0; m < 3; m++) {
      const float rs = __expf(-0.5f * lts[m][0]);
      float g = 0.f, h = 0.f;
#pragma unroll
      for (int j = 1; j < DQK; j++) {
        g = fmaf(qr[j], sWk[m][j - 1], g);
        h = fmaf(qr[j], sbk[m][j - 1], h);
      }
      g += sWk[m][DQK - 1];
      h += sbk[m][DQK - 1];
      Aq[m * (N * T) + idx] = (qr[0] - h) * rs;
      Gq[m * (N * T) + idx] = g * rs;
    }
  } else if (b < 128) {
    // ---- binary searches ----
    const int sidx = (b - 32) * 256 + tid;
    const int m = sidx >> 13;
    const int nt = sidx & 8191;
    const int n = nt >> 11;
    const float rt = ref_t[nt];
    const float* tml = ((m == 0) ? t1 : (m == 1 ? t2 : t3)) + n * L;
    int lo = 0, hi = L;
    while (lo < hi) {
      const int mid = (lo + hi) >> 1;
      if (tml[mid] <= rt) lo = mid + 1; else hi = mid;
    }
    Cq[m * 8192 + nt] = lo;
  } else {
    // ---- V transform: 4 rows/thread ----
    const int vb = b - 128;           // 0..1535
    const int mn = vb >> 7;           // m*N+n
    const int m = mn >> 2, n = mn & 3;
    const int lseg = (vb & 127) * 16;
    const float* dm = (m == 0) ? d1 : (m == 1 ? d2 : d3);
    const float* Wv = (m == 0) ? Wv1 : (m == 1 ? Wv2 : Wv3);
    const float* bv = (m == 0) ? bv1 : (m == 1 ? bv2 : bv3);
    const int cdim = tid & 63;
    const int qq = tid >> 6;          // 0..3
    const int l0 = lseg + qq * 4;     // 4 rows per thread

    float Wc[32];
#pragma unroll
    for (int i = 0; i < 32; i++) Wc[i] = Wv[i * 64 + cdim];
    const float bvc = bv[cdim];

    uint hi16[4], lo16[4];
#pragma unroll
    for (int k = 0; k < 4; k++) {
      const float* dp = dm + (size_t)(n * L + l0 + k) * 34;
      float acc = bvc;
#pragma unroll
      for (int i = 0; i < 32; i += 2) {  // rows are 8B-aligned: float2 ok
        const float2 d2 = *(const float2*)&dp[i];
        acc = fmaf(d2.x, Wc[i], acc);
        acc = fmaf(d2.y, Wc[i + 1], acc);
      }
      uint u = __float_as_uint(acc);
      uint h = (u + 0x7fffu + ((u >> 16) & 1u)) & 0xffff0000u;
      float res = acc - __uint_as_float(h);
      uint ul = __float_as_uint(res);
      uint hl = (ul + 0x7fffu + ((ul >> 16) & 1u)) >> 16;
      hi16[k] = h >> 16;
      lo16[k] = hl;
    }
    const int pkh0 = (int)(hi16[0] | (hi16[1] << 16));
    const int pkh1 = (int)(hi16[2] | (hi16[3] << 16));
    const int pkl0 = (int)(lo16[0] | (lo16[1] << 16));
    const int pkl1 = (int)(lo16[2] | (lo16[3] << 16));
    // 4 rows = half an 8l-group at halfsel = (l0>>2)&1.
    ushort_t* dst = VI + (size_t)(mn * 64 + cdim) * (2 * L) +
                    (l0 >> 3) * 16 + ((l0 >> 2) & 1) * 4;
    *(int2*)dst = make_int2(pkh0, pkh1);
    *(int2*)(dst + 8) = make_int2(pkl0, pkl1);

    if (tid < 16) {
      const int l = lseg + tid;
      X[mn * L + l] = dm[(size_t)(n * L + l) * 34 + 33];
    }
  }
}

// =================== main attention kernel (r4 winner, verbatim) ===================
// block = 2 waves, ONE rowgroup (16 t-rows) x full 64 dims; grid 12*128=1536
// (heavy-first -> 4 blocks/CU resident + 512-block LPT refill queue). The two
// waves split each 64-l chunk 32/32; exp+pack computed exactly once
// grid-wide. Counted vmcnt(8) ring, 2 raw barriers/chunk; cross-wave combine
// via LDS at the end. LDS 40KB.
__device__ inline void stage_chunk(ushort_t* dstbuf, const ushort_t* VIb, int ch,
                                   int w, int lane) {
#pragma unroll
  for (int i = 0; i < 8; i++) {
    const int n = (w * 8 + i) * 64 + lane;   // lds 16B-unit index 0..1023
    const int d = n >> 4;                    // dim row 0..63
    const int s = n & 15;                    // swizzled unit slot
    const int u = (s - d) & 15;              // original unit within row-chunk
    const ushort_t* src = VIb + (size_t)d * 4096 + ch * 128 + u * 8;
    __builtin_amdgcn_global_load_lds(
        (const __attribute__((address_space(1))) void*)src,
        (__attribute__((address_space(3))) void*)(dstbuf + n * 8),
        16, 0, 0);
  }
}

__global__ __launch_bounds__(128, 2) void mm_attn_main(
    const ushort_t* __restrict__ VI, const float* __restrict__ X,
    const float* __restrict__ Aq, const float* __restrict__ Gq, const int* __restrict__ Cq,
    float* __restrict__ out) {
  __shared__ ushort_t sbuf[2][8192];  // 2 x 16KB chunk slabs (64 dims x 64 l)
  __shared__ float sx[2048];          // full X row for this mn (8KB) -> 40KB

  const int b = blockIdx.x;
  const int mn = b % 12;
  const int rg = 127 - (b / 12);  // heavy rowgroups (large c) first

  const int tid = threadIdx.x;
  const int lane = tid & 63;
  const int w = tid >> 6;              // wave 0/1: l-half of each chunk
  const int q = lane >> 4;
  const int m16 = lane & 15;

  const int tbase = mn * T + rg * 16;

  const int c = Cq[tbase + m16];
  const int cmax = __shfl(c, 15, 64);  // c monotone in t
  const int cmin = __shfl(c, 0, 64);
  const int nch = (cmax + 63) >> 6;    // block-uniform chunk count

  const float a = Aq[tbase + m16];
  const float g = Gq[tbase + m16];

  f32x4 acc[4];  // [hh*2+ct]: cols hh*32 + ct*16 + m16 (partial over this wave's l)
#pragma unroll
  for (int i = 0; i < 4; i++) acc[i] = (f32x4){0.f, 0.f, 0.f, 0.f};
  float z = 0.f;

  const ushort_t* VIb = VI + (size_t)(mn * 64) * 4096;
  const float* xg = X + mn * L;

  // hoisted swizzled B-fragment offsets (ushorts): dim row d, unit u stored
  // at d*16 + ((u+d)&15); this wave reads groups w*4+q (hi/lo parts).
  int oh[2][2], ol[2][2];
#pragma unroll
  for (int hh = 0; hh < 2; hh++) {
#pragma unroll
    for (int ct = 0; ct < 2; ct++) {
      const int d = hh * 32 + ct * 16 + m16;
      const int u0 = (w * 4 + q) * 2;
      oh[hh][ct] = d * 128 + (((u0 + 0) + d) & 15) * 8;
      ol[hh][ct] = d * 128 + (((u0 + 1) + d) & 15) * 8;
    }
  }

  // prologue: stage X (8KB) + chunk 0
#pragma unroll
  for (int i = 0; i < 4; i++) {
    const float* src = xg + (i * 128 + tid) * 4;
    __builtin_amdgcn_global_load_lds(
        (const __attribute__((address_space(1))) void*)src,
        (__attribute__((address_space(3))) void*)(sx + (i * 128 + tid) * 4),
        16, 0, 0);
  }
  if (nch > 0) stage_chunk(sbuf[0], VIb, 0, w, lane);

  for (int ch = 0; ch < nch; ch++) {
    if (ch + 1 < nch) {
      stage_chunk(sbuf[(ch + 1) & 1], VIb, ch + 1, w, lane);
      asm volatile("s_waitcnt vmcnt(8)" ::: "memory");  // this chunk done; next in flight
    } else {
      asm volatile("s_waitcnt vmcnt(0)" ::: "memory");
    }
    asm volatile("" ::: "memory");
    __builtin_amdgcn_s_barrier();  // both waves' halves staged
    asm volatile("" ::: "memory");

    const int kbase = (ch << 6) + w * 32;  // this wave's 32-l k-tile
    if (kbase < cmax) {
      const int k0 = kbase + q * 8;
      const float4 xa = *(const float4*)&sx[k0];
      const float4 xb = *(const float4*)&sx[k0 + 4];
      const float xs[8] = {xa.x, xa.y, xa.z, xa.w, xb.x, xb.y, xb.z, xb.w};
      float wv[8];
      if (kbase + 32 <= cmin) {  // all 16 rows fully active in this k-tile
#pragma unroll
        for (int jj = 0; jj < 8; jj++) {
          const float d = fmaf(-g, xs[jj], a);
          wv[jj] = __expf(-d * d);
          z += wv[jj];
        }
      } else {
#pragma unroll
        for (int jj = 0; jj < 8; jj++) {
          const float d = fmaf(-g, xs[jj], a);
          const float e = __expf(-d * d);
          wv[jj] = (k0 + jj < c) ? e : 0.f;
          z += wv[jj];
        }
      }
      PK8 ph, pl;
#pragma unroll
      for (int p2 = 0; p2 < 4; p2++) {
        const uint u0 = __float_as_uint(wv[2 * p2]);
        const uint u1 = __float_as_uint(wv[2 * p2 + 1]);
        const uint h0 = u0 & 0xffff0000u, h1 = u1 & 0xffff0000u;
        const float l0f = wv[2 * p2] - __uint_as_float(h0);
        const float l1f = wv[2 * p2 + 1] - __uint_as_float(h1);
        ph.i[p2] = (int)((h0 >> 16) | h1);
        pl.i[p2] = (int)((__float_as_uint(l0f) >> 16) | (__float_as_uint(l1f) & 0xffff0000u));
      }
      const bf16x8 ahi = ph.s, alo = pl.s;
      const ushort_t* buf = sbuf[ch & 1];
#pragma unroll
      for (int hh = 0; hh < 2; hh++) {
#pragma unroll
        for (int ct = 0; ct < 2; ct++) {
          const bf16x8 bh = *(const bf16x8*)(buf + oh[hh][ct]);
          const bf16x8 bl = *(const bf16x8*)(buf + ol[hh][ct]);
          acc[hh * 2 + ct] =
              __builtin_amdgcn_mfma_f32_16x16x32_bf16(ahi, bh, acc[hh * 2 + ct], 0, 0, 0);
          acc[hh * 2 + ct] =
              __builtin_amdgcn_mfma_f32_16x16x32_bf16(ahi, bl, acc[hh * 2 + ct], 0, 0, 0);
          acc[hh * 2 + ct] =
              __builtin_amdgcn_mfma_f32_16x16x32_bf16(alo, bh, acc[hh * 2 + ct], 0, 0, 0);
        }
      }
    }

    asm volatile("" ::: "memory");
    __builtin_amdgcn_s_barrier();  // reads done before next stage overwrites
    asm volatile("" ::: "memory");
  }

  // z: reduce q-replicas (each octet covered disjoint l within this wave)
  z += __shfl_xor(z, 16, 64);
  z += __shfl_xor(z, 32, 64);

  // cross-wave combine via LDS: wave w outputs dims [w*32, w*32+32) and
  // hands its partial of the OTHER half (quadrants hh = w^1) across.
  float* sc = (float*)sbuf;
  const int ow = w ^ 1;
#pragma unroll
  for (int p = 0; p < 2; p++)
    *(f32x4*)&sc[((w * 2 + p) * 64 + lane) * 4] = acc[ow * 2 + p];
  sc[1024 + w * 64 + lane] = z;
  __syncthreads();
  const float zt = z + sc[1024 + ow * 64 + lane];
  f32x4 r[2];
#pragma unroll
  for (int p = 0; p < 2; p++)
    r[p] = acc[w * 2 + p] + *(const f32x4*)&sc[((ow * 2 + p) * 64 + lane) * 4];

#pragma unroll
  for (int rr = 0; rr < 4; rr++) {
    const int row = q * 4 + rr;
    const float zr = __shfl(zt, row, 64);
    const int cr = __shfl(c, row, 64);
    const float inv = 1.0f / (zr + (float)(L - cr));
#pragma unroll
    for (int p = 0; p < 2; p++) {
      out[(size_t)(tbase + row) * 64 + w * 32 + p * 16 + m16] = r[p][rr] * inv;
    }
  }
}

}  // namespace

extern "C" void kernel_launch(void* const* d_in, const int* in_sizes, int n_in,
                              void* d_out, int out_size, void* d_ws, size_t ws_size,
                              hipStream_t stream) {
  const float* ref_data = (const float*)d_in[0];
  const float* ref_t = (const float*)d_in[1];
  const float* m1_data = (const float*)d_in[2];
  const float* m1_t = (const float*)d_in[3];
  const float* m2_data = (const float*)d_in[4];
  const float* m2_t = (const float*)d_in[5];
  const float* m3_data = (const float*)d_in[6];
  const float* m3_t = (const float*)d_in[7];
  const float* Wq = (const float*)d_in[8];
  const float* Wk1 = (const float*)d_in[9];
  const float* bk1 = (const float*)d_in[10];
  const float* Wv1 = (const float*)d_in[11];
  const float* bv1 = (const float*)d_in[12];
  const float* lt1 = (const float*)d_in[13];
  const float* Wk2 = (const float*)d_in[14];
  const float* bk2 = (const float*)d_in[15];
  const float* Wv2 = (const float*)d_in[16];
  const float* bv2 = (const float*)d_in[17];
  const float* lt2 = (const float*)d_in[18];
  const float* Wk3 = (const float*)d_in[19];
  const float* bk3 = (const float*)d_in[20];
  const float* Wv3 = (const float*)d_in[21];
  const float* bv3 = (const float*)d_in[22];
  const float* lt3 = (const float*)d_in[23];

  float* ws = (float*)d_ws;
  ushort_t* VI = (ushort_t*)ws;                 // VI_SZ float slots
  float* Xw = ws + VI_SZ;                       // X_SZ
  float* Aq = Xw + X_SZ;                        // A_SZ
  float* Gq = Aq + A_SZ;                        // A_SZ
  int* Cq = (int*)(Gq + A_SZ);                  // A_SZ

  mm_prep<<<dim3(1664), dim3(256), 0, stream>>>(
      ref_data, ref_t, m1_data, m1_t, m2_data, m2_t, m3_data, m3_t, Wq,
      Wk1, bk1, Wv1, bv1, lt1, Wk2, bk2, Wv2, bv2, lt2, Wk3, bk3, Wv3, bv3, lt3,
      Aq, Gq, Cq, VI, Xw);
  mm_attn_main<<<dim3(12 * 128), dim3(128), 0, stream>>>(
      VI, Xw, Aq, Gq, Cq, (float*)d_out);
}

// Round 8
// 145.995 us; speedup vs baseline: 1.1167x; 1.0108x over previous
//
#include <hip/hip_runtime.h>

namespace {

typedef unsigned int uint;
typedef unsigned short ushort_t;
typedef __attribute__((ext_vector_type(8))) short bf16x8;
typedef __attribute__((ext_vector_type(4))) float f32x4;

constexpr int N = 4, T = 2048, L = 2048;
constexpr int DQIN = 32, DQK = 64;

// workspace layout (float-sized slots); ~6.5 MB
// VI is now FRAGMENT-MAJOR: per mn, 32 chunks x [w 0/1][quadrant hh*2+ct]
// [hi/lo][lane 0..63][8 ushorts]  -> each wave's MFMA B-operand is one
// contiguous lane-coalesced 1KB block (16B/lane).
constexpr int VI_SZ = 3 * N * 64 * L;  // ushort pairs, as float slots (unchanged size)
constexpr int X_SZ = 3 * N * L;
constexpr int A_SZ = 3 * N * T;

union PK8 { int i[4]; bf16x8 s; };

// =================== fused prep kernel ===================
// [0,32): Q->a,g for ALL 3 modalities (qr once; weights via LDS broadcast).
// [32,128): binary searches. Both dispatched FIRST so their latency chains
// hide under the V bulk (r6 lesson).
// [128,1664): V transform (4 rows/thread, float2 row loads), writing the
// fragment-major VI layout.
__global__ __launch_bounds__(256) void mm_prep(
    const float* __restrict__ ref_data, const float* __restrict__ ref_t,
    const float* __restrict__ d1, const float* __restrict__ t1,
    const float* __restrict__ d2, const float* __restrict__ t2,
    const float* __restrict__ d3, const float* __restrict__ t3,
    const float* __restrict__ Wq,
    const float* __restrict__ Wk1, const float* __restrict__ bk1,
    const float* __restrict__ Wv1, const float* __restrict__ bv1, const float* __restrict__ lt1,
    const float* __restrict__ Wk2, const float* __restrict__ bk2,
    const float* __restrict__ Wv2, const float* __restrict__ bv2, const float* __restrict__ lt2,
    const float* __restrict__ Wk3, const float* __restrict__ bk3,
    const float* __restrict__ Wv3, const float* __restrict__ bv3, const float* __restrict__ lt3,
    float* __restrict__ Aq, float* __restrict__ Gq, int* __restrict__ Cq,
    ushort_t* __restrict__ VI, float* __restrict__ X) {
  const int b = blockIdx.x;
  const int tid = threadIdx.x;

  if (b < 32) {
    // ---- Q path: one thread per t-row; qr once, 3 modality epilogues ----
    const int idx = b * 256 + tid;  // n*T + t
    __shared__ float sWq[DQIN * DQK];
    __shared__ float sWk[3][DQK];
    __shared__ float sbk[3][DQK];
    for (int i = tid; i < DQIN * DQK; i += 256) sWq[i] = Wq[i];
    if (tid < DQK) {
      sWk[0][tid] = Wk1[tid]; sbk[0][tid] = bk1[tid];
      sWk[1][tid] = Wk2[tid]; sbk[1][tid] = bk2[tid];
      sWk[2][tid] = Wk3[tid]; sbk[2][tid] = bk3[tid];
    }
    __syncthreads();
    float x[DQIN];
    const float* rp = ref_data + idx * DQIN;
#pragma unroll
    for (int i = 0; i < DQIN; i++) x[i] = rp[i];
    float qr[DQK];
#pragma unroll
    for (int j = 0; j < DQK; j += 4) {
      float4 acc4 = make_float4(0.f, 0.f, 0.f, 0.f);
#pragma unroll
      for (int i = 0; i < DQIN; i++) {
        const float4 w = *(const float4*)&sWq[i * DQK + j];
        acc4.x = fmaf(x[i], w.x, acc4.x);
        acc4.y = fmaf(x[i], w.y, acc4.y);
        acc4.z = fmaf(x[i], w.z, acc4.z);
        acc4.w = fmaf(x[i], w.w, acc4.w);
      }
      qr[j] = acc4.x; qr[j + 1] = acc4.y; qr[j + 2] = acc4.z; qr[j + 3] = acc4.w;
    }
    const float* lts[3] = {lt1, lt2, lt3};
#pragma unroll
    for (int m = 0; m < 3; m++) {
      const float rs = __expf(-0.5f * lts[m][0]);
      float g = 0.f, h = 0.f;
#pragma unroll
      for (int j = 1; j < DQK; j++) {
        g = fmaf(qr[j], sWk[m][j - 1], g);
        h = fmaf(qr[j], sbk[m][j - 1], h);
      }
      g += sWk[m][DQK - 1];
      h += sbk[m][DQK - 1];
      Aq[m * (N * T) + idx] = (qr[0] - h) * rs;
      Gq[m * (N * T) + idx] = g * rs;
    }
  } else if (b < 128) {
    // ---- binary searches ----
    const int sidx = (b - 32) * 256 + tid;
    const int m = sidx >> 13;
    const int nt = sidx & 8191;
    const int n = nt >> 11;
    const float rt = ref_t[nt];
    const float* tml = ((m == 0) ? t1 : (m == 1 ? t2 : t3)) + n * L;
    int lo = 0, hi = L;
    while (lo < hi) {
      const int mid = (lo + hi) >> 1;
      if (tml[mid] <= rt) lo = mid + 1; else hi = mid;
    }
    Cq[m * 8192 + nt] = lo;
  } else {
    // ---- V transform: 4 rows/thread, fragment-major store ----
    const int vb = b - 128;           // 0..1535
    const int mn = vb >> 7;           // m*N+n
    const int m = mn >> 2, n = mn & 3;
    const int lseg = (vb & 127) * 16;
    const float* dm = (m == 0) ? d1 : (m == 1 ? d2 : d3);
    const float* Wv = (m == 0) ? Wv1 : (m == 1 ? Wv2 : Wv3);
    const float* bv = (m == 0) ? bv1 : (m == 1 ? bv2 : bv3);
    const int cdim = tid & 63;
    const int qq = tid >> 6;          // 0..3
    const int l0 = lseg + qq * 4;     // 4 rows per thread

    float Wc[32];
#pragma unroll
    for (int i = 0; i < 32; i++) Wc[i] = Wv[i * 64 + cdim];
    const float bvc = bv[cdim];

    uint hi16[4], lo16[4];
#pragma unroll
    for (int k = 0; k < 4; k++) {
      const float* dp = dm + (size_t)(n * L + l0 + k) * 34;
      float acc = bvc;
#pragma unroll
      for (int i = 0; i < 32; i += 2) {  // rows are 8B-aligned: float2 ok
        const float2 dd = *(const float2*)&dp[i];
        acc = fmaf(dd.x, Wc[i], acc);
        acc = fmaf(dd.y, Wc[i + 1], acc);
      }
      uint u = __float_as_uint(acc);
      uint h = (u + 0x7fffu + ((u >> 16) & 1u)) & 0xffff0000u;
      float res = acc - __uint_as_float(h);
      uint ul = __float_as_uint(res);
      uint hl = (ul + 0x7fffu + ((ul >> 16) & 1u)) >> 16;
      hi16[k] = h >> 16;
      lo16[k] = hl;
    }
    const int pkh0 = (int)(hi16[0] | (hi16[1] << 16));
    const int pkh1 = (int)(hi16[2] | (hi16[3] << 16));
    const int pkl0 = (int)(lo16[0] | (lo16[1] << 16));
    const int pkl1 = (int)(lo16[2] | (lo16[3] << 16));

    // fragment-major destination:
    //   hh = cdim>>5, ct = (cdim>>4)&1, m16 = cdim&15
    //   ch = l0>>6, w = (l0>>5)&1, q = (l0>>3)&3, half = (l0>>2)&1
    //   lane = q*16+m16;  hi block at +0, lo block at +512 ushorts
    const int hh = cdim >> 5, ct = (cdim >> 4) & 1, m16f = cdim & 15;
    const int ch = l0 >> 6, wf = (l0 >> 5) & 1, qf = (l0 >> 3) & 3, half = (l0 >> 2) & 1;
    const int lanef = qf * 16 + m16f;
    ushort_t* dst = VI + (size_t)mn * 262144 + (size_t)ch * 8192 + wf * 4096 +
                    (hh * 2 + ct) * 1024 + lanef * 8 + half * 4;
    *(int2*)dst = make_int2(pkh0, pkh1);          // hi halves
    *(int2*)(dst + 512) = make_int2(pkl0, pkl1);  // lo halves

    if (tid < 16) {
      const int l = lseg + tid;
      X[mn * L + l] = dm[(size_t)(n * L + l) * 34 + 33];
    }
  }
}

// =================== main attention kernel ===================
// BARRIER-FREE main loop (r3's independence + r0's coalescing): block =
// 2 waves, one rowgroup (16 t-rows) x 64 dims; wave w owns k-tiles
// [ch*64+w*32, +32) and iterates exactly its own chunk count. Per chunk:
// 2 float4 X loads (1-deep register prefetch), exp+pack once, then 8
// coalesced global_load_dwordx4 B-fragment loads (fragment-major VI: 16B
// per lane, contiguous 1KB per wave-quadrant) feeding 12 MFMAs. No LDS
// staging, no barriers, no vmcnt asm -> compiler freely hoists next-chunk
// loads under MFMAs, and LDS drops 40KB -> 4.6KB so residency is ~8
// blocks/CU (16 waves, 2x r7). r3's failure was per-lane 16B loads at 8KB
// stride (uncoalesced) -- this layout is the fix. Single __syncthreads at
// the end for the cross-wave combine. Per-quadrant accumulation order
// unchanged -> output bitwise identical to r4/r7.
__global__ __launch_bounds__(128, 4) void mm_attn_main(
    const ushort_t* __restrict__ VI, const float* __restrict__ X,
    const float* __restrict__ Aq, const float* __restrict__ Gq, const int* __restrict__ Cq,
    float* __restrict__ out) {
  __shared__ float sc[1152];  // cross-wave combine scratch (4.6KB)

  const int b = blockIdx.x;
  const int mn = b % 12;
  const int rg = 127 - (b / 12);  // heavy rowgroups (large c) first

  const int tid = threadIdx.x;
  const int lane = tid & 63;
  const int w = tid >> 6;              // wave 0/1: l-half of each chunk
  const int q = lane >> 4;
  const int m16 = lane & 15;

  const int tbase = mn * T + rg * 16;

  const int c = Cq[tbase + m16];
  const int cmax = __shfl(c, 15, 64);  // c monotone in t
  const int cmin = __shfl(c, 0, 64);

  const float a = Aq[tbase + m16];
  const float g = Gq[tbase + m16];

  f32x4 acc[4];  // [hh*2+ct]: cols hh*32 + ct*16 + m16 (partial over this wave's l)
#pragma unroll
  for (int i = 0; i < 4; i++) acc[i] = (f32x4){0.f, 0.f, 0.f, 0.f};
  float z = 0.f;

  const float* xg = X + mn * L;

  // per-lane fragment pointers: quadrant (hh,ct) hi-block; lo at +512.
  const ushort_t* pb[4];
#pragma unroll
  for (int hh = 0; hh < 2; hh++)
#pragma unroll
    for (int ct = 0; ct < 2; ct++)
      pb[hh * 2 + ct] = VI + (size_t)mn * 262144 + w * 4096 +
                        (hh * 2 + ct) * 1024 + lane * 8;

  // this wave's chunk count: k-tile kbase = ch*64 + w*32 must be < cmax
  const int nchw = (cmax > w * 32) ? ((cmax - w * 32 + 63) >> 6) : 0;

  // 1-deep register prefetch of X
  float4 xa, xb;
  if (nchw > 0) {
    const int k0 = w * 32 + q * 8;
    xa = *(const float4*)&xg[k0];
    xb = *(const float4*)&xg[k0 + 4];
  }

  for (int ch = 0; ch < nchw; ch++) {
    const int kbase = (ch << 6) + w * 32;
    const int k0 = kbase + q * 8;
    const float4 cxa = xa, cxb = xb;
    if (ch + 1 < nchw) {
      xa = *(const float4*)&xg[k0 + 64];
      xb = *(const float4*)&xg[k0 + 68];
    }
    const float xs[8] = {cxa.x, cxa.y, cxa.z, cxa.w, cxb.x, cxb.y, cxb.z, cxb.w};
    float wv[8];
    if (kbase + 32 <= cmin) {  // all 16 rows fully active in this k-tile
#pragma unroll
      for (int jj = 0; jj < 8; jj++) {
        const float d = fmaf(-g, xs[jj], a);
        wv[jj] = __expf(-d * d);
        z += wv[jj];
      }
    } else {
#pragma unroll
      for (int jj = 0; jj < 8; jj++) {
        const float d = fmaf(-g, xs[jj], a);
        const float e = __expf(-d * d);
        wv[jj] = (k0 + jj < c) ? e : 0.f;
        z += wv[jj];
      }
    }
    PK8 ph, pl;
#pragma unroll
    for (int p2 = 0; p2 < 4; p2++) {
      const uint u0 = __float_as_uint(wv[2 * p2]);
      const uint u1 = __float_as_uint(wv[2 * p2 + 1]);
      const uint h0 = u0 & 0xffff0000u, h1 = u1 & 0xffff0000u;
      const float l0f = wv[2 * p2] - __uint_as_float(h0);
      const float l1f = wv[2 * p2 + 1] - __uint_as_float(h1);
      ph.i[p2] = (int)((h0 >> 16) | h1);
      pl.i[p2] = (int)((__float_as_uint(l0f) >> 16) | (__float_as_uint(l1f) & 0xffff0000u));
    }
    const bf16x8 ahi = ph.s, alo = pl.s;
    const size_t choff = (size_t)ch * 8192;
#pragma unroll
    for (int hh = 0; hh < 2; hh++) {
#pragma unroll
      for (int ct = 0; ct < 2; ct++) {
        const ushort_t* p = pb[hh * 2 + ct] + choff;
        const bf16x8 bh = *(const bf16x8*)p;          // coalesced dwordx4
        const bf16x8 bl = *(const bf16x8*)(p + 512);  // coalesced dwordx4
        acc[hh * 2 + ct] =
            __builtin_amdgcn_mfma_f32_16x16x32_bf16(ahi, bh, acc[hh * 2 + ct], 0, 0, 0);
        acc[hh * 2 + ct] =
            __builtin_amdgcn_mfma_f32_16x16x32_bf16(ahi, bl, acc[hh * 2 + ct], 0, 0, 0);
        acc[hh * 2 + ct] =
            __builtin_amdgcn_mfma_f32_16x16x32_bf16(alo, bh, acc[hh * 2 + ct], 0, 0, 0);
      }
    }
  }

  // z: reduce q-replicas (each octet covered disjoint l within this wave)
  z += __shfl_xor(z, 16, 64);
  z += __shfl_xor(z, 32, 64);

  // cross-wave combine via LDS: wave w outputs dims [w*32, w*32+32) and
  // hands its partial of the OTHER half (quadrants hh = w^1) across.
  const int ow = w ^ 1;
#pragma unroll
  for (int p = 0; p < 2; p++)
    *(f32x4*)&sc[((w * 2 + p) * 64 + lane) * 4] = acc[ow * 2 + p];
  sc[1024 + w * 64 + lane] = z;
  __syncthreads();
  const float zt = z + sc[1024 + ow * 64 + lane];
  f32x4 r[2];
#pragma unroll
  for (int p = 0; p < 2; p++)
    r[p] = acc[w * 2 + p] + *(const f32x4*)&sc[((ow * 2 + p) * 64 + lane) * 4];

#pragma unroll
  for (int rr = 0; rr < 4; rr++) {
    const int row = q * 4 + rr;
    const float zr = __shfl(zt, row, 64);
    const int cr = __shfl(c, row, 64);
    const float inv = 1.0f / (zr + (float)(L - cr));
#pragma unroll
    for (int p = 0; p < 2; p++) {
      out[(size_t)(tbase + row) * 64 + w * 32 + p * 16 + m16] = r[p][rr] * inv;
    }
  }
}

}  // namespace

extern "C" void kernel_launch(void* const* d_in, const int* in_sizes, int n_in,
                              void* d_out, int out_size, void* d_ws, size_t ws_size,
                              hipStream_t stream) {
  const float* ref_data = (const float*)d_in[0];
  const float* ref_t = (const float*)d_in[1];
  const float* m1_data = (const float*)d_in[2];
  const float* m1_t = (const float*)d_in[3];
  const float* m2_data = (const float*)d_in[4];
  const float* m2_t = (const float*)d_in[5];
  const float* m3_data = (const float*)d_in[6];
  const float* m3_t = (const float*)d_in[7];
  const float* Wq = (const float*)d_in[8];
  const float* Wk1 = (const float*)d_in[9];
  const float* bk1 = (const float*)d_in[10];
  const float* Wv1 = (const float*)d_in[11];
  const float* bv1 = (const float*)d_in[12];
  const float* lt1 = (const float*)d_in[13];
  const float* Wk2 = (const float*)d_in[14];
  const float* bk2 = (const float*)d_in[15];
  const float* Wv2 = (const float*)d_in[16];
  const float* bv2 = (const float*)d_in[17];
  const float* lt2 = (const float*)d_in[18];
  const float* Wk3 = (const float*)d_in[19];
  const float* bk3 = (const float*)d_in[20];
  const float* Wv3 = (const float*)d_in[21];
  const float* bv3 = (const float*)d_in[22];
  const float* lt3 = (const float*)d_in[23];

  float* ws = (float*)d_ws;
  ushort_t* VI = (ushort_t*)ws;                 // VI_SZ float slots
  float* Xw = ws + VI_SZ;                       // X_SZ
  float* Aq = Xw + X_SZ;                        // A_SZ
  float* Gq = Aq + A_SZ;                        // A_SZ
  int* Cq = (int*)(Gq + A_SZ);                  // A_SZ

  mm_prep<<<dim3(1664), dim3(256), 0, stream>>>(
      ref_data, ref_t, m1_data, m1_t, m2_data, m2_t, m3_data, m3_t, Wq,
      Wk1, bk1, Wv1, bv1, lt1, Wk2, bk2, Wv2, bv2, lt2, Wk3, bk3, Wv3, bv3, lt3,
      Aq, Gq, Cq, VI, Xw);
  mm_attn_main<<<dim3(12 * 128), dim3(128), 0, stream>>>(
      VI, Xw, Aq, Gq, Cq, (float*)d_out);
}

// Round 9
// 144.538 us; speedup vs baseline: 1.1279x; 1.0101x over previous
//
#include <hip/hip_runtime.h>

namespace {

typedef unsigned int uint;
typedef unsigned short ushort_t;
typedef __attribute__((ext_vector_type(8))) short bf16x8;
typedef __attribute__((ext_vector_type(4))) float f32x4;

constexpr int N = 4, T = 2048, L = 2048;
constexpr int DQIN = 32, DQK = 64;

// workspace layout (float-sized slots); ~6.5 MB
// VI is FRAGMENT-MAJOR: per mn, 32 chunks x [w 0/1][quadrant hh*2+ct]
// [hi/lo][lane 0..63][8 ushorts]  -> each wave's MFMA B-operand is one
// contiguous lane-coalesced 1KB block (16B/lane).
constexpr int VI_SZ = 3 * N * 64 * L;  // ushort pairs, as float slots
constexpr int X_SZ = 3 * N * L;
constexpr int A_SZ = 3 * N * T;

union PK8 { int i[4]; bf16x8 s; };

// =================== fused prep kernel ===================
// [0,32): Q->a,g for ALL 3 modalities (qr once; weights via LDS broadcast).
// [32,128): binary searches. Both dispatched FIRST so their latency chains
// hide under the V bulk (r6 lesson).
// [128,1664): V transform (4 rows/thread, float2 row loads), writing the
// fragment-major VI layout.
__global__ __launch_bounds__(256) void mm_prep(
    const float* __restrict__ ref_data, const float* __restrict__ ref_t,
    const float* __restrict__ d1, const float* __restrict__ t1,
    const float* __restrict__ d2, const float* __restrict__ t2,
    const float* __restrict__ d3, const float* __restrict__ t3,
    const float* __restrict__ Wq,
    const float* __restrict__ Wk1, const float* __restrict__ bk1,
    const float* __restrict__ Wv1, const float* __restrict__ bv1, const float* __restrict__ lt1,
    const float* __restrict__ Wk2, const float* __restrict__ bk2,
    const float* __restrict__ Wv2, const float* __restrict__ bv2, const float* __restrict__ lt2,
    const float* __restrict__ Wk3, const float* __restrict__ bk3,
    const float* __restrict__ Wv3, const float* __restrict__ bv3, const float* __restrict__ lt3,
    float* __restrict__ Aq, float* __restrict__ Gq, int* __restrict__ Cq,
    ushort_t* __restrict__ VI, float* __restrict__ X) {
  const int b = blockIdx.x;
  const int tid = threadIdx.x;

  if (b < 32) {
    // ---- Q path: one thread per t-row; qr once, 3 modality epilogues ----
    const int idx = b * 256 + tid;  // n*T + t
    __shared__ float sWq[DQIN * DQK];
    __shared__ float sWk[3][DQK];
    __shared__ float sbk[3][DQK];
    for (int i = tid; i < DQIN * DQK; i += 256) sWq[i] = Wq[i];
    if (tid < DQK) {
      sWk[0][tid] = Wk1[tid]; sbk[0][tid] = bk1[tid];
      sWk[1][tid] = Wk2[tid]; sbk[1][tid] = bk2[tid];
      sWk[2][tid] = Wk3[tid]; sbk[2][tid] = bk3[tid];
    }
    __syncthreads();
    float x[DQIN];
    const float* rp = ref_data + idx * DQIN;
#pragma unroll
    for (int i = 0; i < DQIN; i++) x[i] = rp[i];
    float qr[DQK];
#pragma unroll
    for (int j = 0; j < DQK; j += 4) {
      float4 acc4 = make_float4(0.f, 0.f, 0.f, 0.f);
#pragma unroll
      for (int i = 0; i < DQIN; i++) {
        const float4 w = *(const float4*)&sWq[i * DQK + j];
        acc4.x = fmaf(x[i], w.x, acc4.x);
        acc4.y = fmaf(x[i], w.y, acc4.y);
        acc4.z = fmaf(x[i], w.z, acc4.z);
        acc4.w = fmaf(x[i], w.w, acc4.w);
      }
      qr[j] = acc4.x; qr[j + 1] = acc4.y; qr[j + 2] = acc4.z; qr[j + 3] = acc4.w;
    }
    const float* lts[3] = {lt1, lt2, lt3};
#pragma unroll
    for (int m = 0; m < 3; m++) {
      const float rs = __expf(-0.5f * lts[m][0]);
      float g = 0.f, h = 0.f;
#pragma unroll
      for (int j = 1; j < DQK; j++) {
        g = fmaf(qr[j], sWk[m][j - 1], g);
        h = fmaf(qr[j], sbk[m][j - 1], h);
      }
      g += sWk[m][DQK - 1];
      h += sbk[m][DQK - 1];
      Aq[m * (N * T) + idx] = (qr[0] - h) * rs;
      Gq[m * (N * T) + idx] = g * rs;
    }
  } else if (b < 128) {
    // ---- binary searches ----
    const int sidx = (b - 32) * 256 + tid;
    const int m = sidx >> 13;
    const int nt = sidx & 8191;
    const int n = nt >> 11;
    const float rt = ref_t[nt];
    const float* tml = ((m == 0) ? t1 : (m == 1 ? t2 : t3)) + n * L;
    int lo = 0, hi = L;
    while (lo < hi) {
      const int mid = (lo + hi) >> 1;
      if (tml[mid] <= rt) lo = mid + 1; else hi = mid;
    }
    Cq[m * 8192 + nt] = lo;
  } else {
    // ---- V transform: 4 rows/thread, fragment-major store ----
    const int vb = b - 128;           // 0..1535
    const int mn = vb >> 7;           // m*N+n
    const int m = mn >> 2, n = mn & 3;
    const int lseg = (vb & 127) * 16;
    const float* dm = (m == 0) ? d1 : (m == 1 ? d2 : d3);
    const float* Wv = (m == 0) ? Wv1 : (m == 1 ? Wv2 : Wv3);
    const float* bv = (m == 0) ? bv1 : (m == 1 ? bv2 : bv3);
    const int cdim = tid & 63;
    const int qq = tid >> 6;          // 0..3
    const int l0 = lseg + qq * 4;     // 4 rows per thread

    float Wc[32];
#pragma unroll
    for (int i = 0; i < 32; i++) Wc[i] = Wv[i * 64 + cdim];
    const float bvc = bv[cdim];

    uint hi16[4], lo16[4];
#pragma unroll
    for (int k = 0; k < 4; k++) {
      const float* dp = dm + (size_t)(n * L + l0 + k) * 34;
      float acc = bvc;
#pragma unroll
      for (int i = 0; i < 32; i += 2) {  // rows are 8B-aligned: float2 ok
        const float2 dd = *(const float2*)&dp[i];
        acc = fmaf(dd.x, Wc[i], acc);
        acc = fmaf(dd.y, Wc[i + 1], acc);
      }
      uint u = __float_as_uint(acc);
      uint h = (u + 0x7fffu + ((u >> 16) & 1u)) & 0xffff0000u;
      float res = acc - __uint_as_float(h);
      uint ul = __float_as_uint(res);
      uint hl = (ul + 0x7fffu + ((ul >> 16) & 1u)) >> 16;
      hi16[k] = h >> 16;
      lo16[k] = hl;
    }
    const int pkh0 = (int)(hi16[0] | (hi16[1] << 16));
    const int pkh1 = (int)(hi16[2] | (hi16[3] << 16));
    const int pkl0 = (int)(lo16[0] | (lo16[1] << 16));
    const int pkl1 = (int)(lo16[2] | (lo16[3] << 16));

    // fragment-major destination:
    //   hh = cdim>>5, ct = (cdim>>4)&1, m16 = cdim&15
    //   ch = l0>>6, w = (l0>>5)&1, q = (l0>>3)&3, half = (l0>>2)&1
    //   lane = q*16+m16;  hi block at +0, lo block at +512 ushorts
    const int hh = cdim >> 5, ct = (cdim >> 4) & 1, m16f = cdim & 15;
    const int ch = l0 >> 6, wf = (l0 >> 5) & 1, qf = (l0 >> 3) & 3, half = (l0 >> 2) & 1;
    const int lanef = qf * 16 + m16f;
    ushort_t* dst = VI + (size_t)mn * 262144 + (size_t)ch * 8192 + wf * 4096 +
                    (hh * 2 + ct) * 1024 + lanef * 8 + half * 4;
    *(int2*)dst = make_int2(pkh0, pkh1);          // hi halves
    *(int2*)(dst + 512) = make_int2(pkl0, pkl1);  // lo halves

    if (tid < 16) {
      const int l = lseg + tid;
      X[mn * L + l] = dm[(size_t)(n * L + l) * 34 + 33];
    }
  }
}

// =================== main attention kernel ===================
// r8 structure (barrier-free, fragment-major coalesced B loads) + XCD-aware
// block re-index (T1). HW round-robins consecutive blockIdx across the 8
// XCDs; r8's `mn = b%12` made every XCD touch all 12 mn -> 6MB VI working
// set per 4MB XCD-L2 -> guaranteed thrash, VI re-reads (~400MB total)
// served by slower L3. New decode: wid = (b&7)*192 + (b>>3) gives each XCD
// a contiguous 192-wid range = exactly 2 mn (<=1MB VI in its L2). Within
// each XCD slice, the two mn runs (mnA tail-ranks + mnB head-ranks, both
// rg = 127-rank so low rank = heavy) are dispatched in merged
// weight-descending order -> per-XCD LPT preserved. Per-block work
// untouched -> output bitwise identical to r8.
__global__ __launch_bounds__(128, 4) void mm_attn_main(
    const ushort_t* __restrict__ VI, const float* __restrict__ X,
    const float* __restrict__ Aq, const float* __restrict__ Gq, const int* __restrict__ Cq,
    float* __restrict__ out) {
  __shared__ float sc[1152];  // cross-wave combine scratch (4.6KB)

  const int b = blockIdx.x;
  // ---- XCD-aware decode (bijective over 1536) ----
  const int x = b & 7;        // XCD (HW round-robin assumption; perf-only)
  const int s = b >> 3;       // dispatch slot within XCD, 0..191
  const int ra = (x * 192) & 127;      // mnA's first in-slice rank
  const int mnA = (x * 192) >> 7;      // slice = mnA ranks [ra,128) + mnB ranks [0, ra+64)
  int mn, rank;
  if (s < ra) {                        // mnB's top heavies (rg 127-s)
    mn = mnA + 1; rank = s;
  } else if (s < ra + 128) {           // merged alternation, equal weights
    const int t = s - ra;
    mn = (t & 1) ? (mnA + 1) : mnA;
    rank = ra + (t >> 1);
  } else {                             // mnA's light tail
    mn = mnA; rank = s - 64;
  }
  const int rg = 127 - rank;           // heavy (large c) = early dispatch

  const int tid = threadIdx.x;
  const int lane = tid & 63;
  const int w = tid >> 6;              // wave 0/1: l-half of each chunk
  const int q = lane >> 4;
  const int m16 = lane & 15;

  const int tbase = mn * T + rg * 16;

  const int c = Cq[tbase + m16];
  const int cmax = __shfl(c, 15, 64);  // c monotone in t
  const int cmin = __shfl(c, 0, 64);

  const float a = Aq[tbase + m16];
  const float g = Gq[tbase + m16];

  f32x4 acc[4];  // [hh*2+ct]: cols hh*32 + ct*16 + m16 (partial over this wave's l)
#pragma unroll
  for (int i = 0; i < 4; i++) acc[i] = (f32x4){0.f, 0.f, 0.f, 0.f};
  float z = 0.f;

  const float* xg = X + mn * L;

  // per-lane fragment pointers: quadrant (hh,ct) hi-block; lo at +512.
  const ushort_t* pb[4];
#pragma unroll
  for (int hh = 0; hh < 2; hh++)
#pragma unroll
    for (int ct = 0; ct < 2; ct++)
      pb[hh * 2 + ct] = VI + (size_t)mn * 262144 + w * 4096 +
                        (hh * 2 + ct) * 1024 + lane * 8;

  // this wave's chunk count: k-tile kbase = ch*64 + w*32 must be < cmax
  const int nchw = (cmax > w * 32) ? ((cmax - w * 32 + 63) >> 6) : 0;

  // 1-deep register prefetch of X
  float4 xa, xb;
  if (nchw > 0) {
    const int k0 = w * 32 + q * 8;
    xa = *(const float4*)&xg[k0];
    xb = *(const float4*)&xg[k0 + 4];
  }

  for (int ch = 0; ch < nchw; ch++) {
    const int kbase = (ch << 6) + w * 32;
    const int k0 = kbase + q * 8;
    const float4 cxa = xa, cxb = xb;
    if (ch + 1 < nchw) {
      xa = *(const float4*)&xg[k0 + 64];
      xb = *(const float4*)&xg[k0 + 68];
    }
    const float xs[8] = {cxa.x, cxa.y, cxa.z, cxa.w, cxb.x, cxb.y, cxb.z, cxb.w};
    float wv[8];
    if (kbase + 32 <= cmin) {  // all 16 rows fully active in this k-tile
#pragma unroll
      for (int jj = 0; jj < 8; jj++) {
        const float d = fmaf(-g, xs[jj], a);
        wv[jj] = __expf(-d * d);
        z += wv[jj];
      }
    } else {
#pragma unroll
      for (int jj = 0; jj < 8; jj++) {
        const float d = fmaf(-g, xs[jj], a);
        const float e = __expf(-d * d);
        wv[jj] = (k0 + jj < c) ? e : 0.f;
        z += wv[jj];
      }
    }
    PK8 ph, pl;
#pragma unroll
    for (int p2 = 0; p2 < 4; p2++) {
      const uint u0 = __float_as_uint(wv[2 * p2]);
      const uint u1 = __float_as_uint(wv[2 * p2 + 1]);
      const uint h0 = u0 & 0xffff0000u, h1 = u1 & 0xffff0000u;
      const float l0f = wv[2 * p2] - __uint_as_float(h0);
      const float l1f = wv[2 * p2 + 1] - __uint_as_float(h1);
      ph.i[p2] = (int)((h0 >> 16) | h1);
      pl.i[p2] = (int)((__float_as_uint(l0f) >> 16) | (__float_as_uint(l1f) & 0xffff0000u));
    }
    const bf16x8 ahi = ph.s, alo = pl.s;
    const size_t choff = (size_t)ch * 8192;
#pragma unroll
    for (int hh = 0; hh < 2; hh++) {
#pragma unroll
      for (int ct = 0; ct < 2; ct++) {
        const ushort_t* p = pb[hh * 2 + ct] + choff;
        const bf16x8 bh = *(const bf16x8*)p;          // coalesced dwordx4
        const bf16x8 bl = *(const bf16x8*)(p + 512);  // coalesced dwordx4
        acc[hh * 2 + ct] =
            __builtin_amdgcn_mfma_f32_16x16x32_bf16(ahi, bh, acc[hh * 2 + ct], 0, 0, 0);
        acc[hh * 2 + ct] =
            __builtin_amdgcn_mfma_f32_16x16x32_bf16(ahi, bl, acc[hh * 2 + ct], 0, 0, 0);
        acc[hh * 2 + ct] =
            __builtin_amdgcn_mfma_f32_16x16x32_bf16(alo, bh, acc[hh * 2 + ct], 0, 0, 0);
      }
    }
  }

  // z: reduce q-replicas (each octet covered disjoint l within this wave)
  z += __shfl_xor(z, 16, 64);
  z += __shfl_xor(z, 32, 64);

  // cross-wave combine via LDS: wave w outputs dims [w*32, w*32+32) and
  // hands its partial of the OTHER half (quadrants hh = w^1) across.
  const int ow = w ^ 1;
#pragma unroll
  for (int p = 0; p < 2; p++)
    *(f32x4*)&sc[((w * 2 + p) * 64 + lane) * 4] = acc[ow * 2 + p];
  sc[1024 + w * 64 + lane] = z;
  __syncthreads();
  const float zt = z + sc[1024 + ow * 64 + lane];
  f32x4 r[2];
#pragma unroll
  for (int p = 0; p < 2; p++)
    r[p] = acc[w * 2 + p] + *(const f32x4*)&sc[((ow * 2 + p) * 64 + lane) * 4];

#pragma unroll
  for (int rr = 0; rr < 4; rr++) {
    const int row = q * 4 + rr;
    const float zr = __shfl(zt, row, 64);
    const int cr = __shfl(c, row, 64);
    const float inv = 1.0f / (zr + (float)(L - cr));
#pragma unroll
    for (int p = 0; p < 2; p++) {
      out[(size_t)(tbase + row) * 64 + w * 32 + p * 16 + m16] = r[p][rr] * inv;
    }
  }
}

}  // namespace

extern "C" void kernel_launch(void* const* d_in, const int* in_sizes, int n_in,
                              void* d_out, int out_size, void* d_ws, size_t ws_size,
                              hipStream_t stream) {
  const float* ref_data = (const float*)d_in[0];
  const float* ref_t = (const float*)d_in[1];
  const float* m1_data = (const float*)d_in[2];
  const float* m1_t = (const float*)d_in[3];
  const float* m2_data = (const float*)d_in[4];
  const float* m2_t = (const float*)d_in[5];
  const float* m3_data = (const float*)d_in[6];
  const float* m3_t = (const float*)d_in[7];
  const float* Wq = (const float*)d_in[8];
  const float* Wk1 = (const float*)d_in[9];
  const float* bk1 = (const float*)d_in[10];
  const float* Wv1 = (const float*)d_in[11];
  const float* bv1 = (const float*)d_in[12];
  const float* lt1 = (const float*)d_in[13];
  const float* Wk2 = (const float*)d_in[14];
  const float* bk2 = (const float*)d_in[15];
  const float* Wv2 = (const float*)d_in[16];
  const float* bv2 = (const float*)d_in[17];
  const float* lt2 = (const float*)d_in[18];
  const float* Wk3 = (const float*)d_in[19];
  const float* bk3 = (const float*)d_in[20];
  const float* Wv3 = (const float*)d_in[21];
  const float* bv3 = (const float*)d_in[22];
  const float* lt3 = (const float*)d_in[23];

  float* ws = (float*)d_ws;
  ushort_t* VI = (ushort_t*)ws;                 // VI_SZ float slots
  float* Xw = ws + VI_SZ;                       // X_SZ
  float* Aq = Xw + X_SZ;                        // A_SZ
  float* Gq = Aq + A_SZ;                        // A_SZ
  int* Cq = (int*)(Gq + A_SZ);                  // A_SZ

  mm_prep<<<dim3(1664), dim3(256), 0, stream>>>(
      ref_data, ref_t, m1_data, m1_t, m2_data, m2_t, m3_data, m3_t, Wq,
      Wk1, bk1, Wv1, bv1, lt1, Wk2, bk2, Wv2, bv2, lt2, Wk3, bk3, Wv3, bv3, lt3,
      Aq, Gq, Cq, VI, Xw);
  mm_attn_main<<<dim3(12 * 128), dim3(128), 0, stream>>>(
      VI, Xw, Aq, Gq, Cq, (float*)d_out);
}